// Round 2
// baseline (568.447 us; speedup 1.0000x reference)
//
#include <hip/hip_runtime.h>
#include <hip/hip_bf16.h>

#define NSITES 100000
#define KOFFS 27
#define CIN 64
#define COUT 128

typedef unsigned short u16;
typedef __attribute__((ext_vector_type(8))) short s16x8;
typedef __attribute__((ext_vector_type(4))) float f32x4;

static __device__ __forceinline__ u16 f2bf(float f) {
    union { float f; unsigned u; } x; x.f = f;
    return (u16)((x.u + 0x7FFFu + ((x.u >> 16) & 1u)) >> 16);
}
static __device__ __forceinline__ float bf2f(u16 v) {
    union { unsigned u; float f; } x; x.u = ((unsigned)v) << 16;
    return x.f;
}

// Barrier with LDS-visibility only: ds/DMA-to-LDS visibility via producer's own
// counted vmcnt + this barrier; never drains consumer/producer vmem to 0.
static __device__ __forceinline__ void lds_barrier() {
    asm volatile("s_waitcnt lgkmcnt(0)" ::: "memory");
    __builtin_amdgcn_s_barrier();
    __builtin_amdgcn_sched_barrier(0);  // no hoisting of LDS reads above the barrier
}

// global(per-lane src) -> LDS(linear lane*16) DMA, 16B per lane
static __device__ __forceinline__ void gld_lds16(const u16* src, u16* dst) {
    __builtin_amdgcn_global_load_lds((const __attribute__((address_space(1))) void*)src,
                                     (__attribute__((address_space(3))) void*)dst,
                                     16, 0, 0);
}

// ---------- prep: transpose/convert weights to bf16 [k][d][c], zero stat partials ----------
__global__ void prep_kernel(const float* __restrict__ W1, const float* __restrict__ W2,
                            const float* __restrict__ Wsk,
                            u16* __restrict__ W1t, u16* __restrict__ W2t,
                            u16* __restrict__ Wskt, float* __restrict__ zero_area) {
    int i = blockIdx.x * 256 + threadIdx.x;
    if (i < 27 * 64 * 128) {
        int k = i / 8192, r = i & 8191, d = r >> 6, c = r & 63;
        W1t[i] = f2bf(W1[k * 8192 + c * 128 + d]);
        return;
    }
    i -= 27 * 64 * 128;
    if (i < 27 * 128 * 128) {
        int k = i / 16384, r = i & 16383, d = r >> 7, c = r & 127;
        W2t[i] = f2bf(W2[k * 16384 + c * 128 + d]);
        return;
    }
    i -= 27 * 128 * 128;
    if (i < 8192) {
        int d = i >> 6, c = i & 63;
        Wskt[i] = f2bf(Wsk[c * 128 + d]);
        return;
    }
    i -= 8192;
    zero_area[i] = 0.0f;  // 4 * 64*128 partial-stat floats
}

// ---------- x (fp32) -> bf16 rows, plus zero sentinel row N ----------
__global__ void convert_x_kernel(const float* __restrict__ x, u16* __restrict__ xb) {
    long long e = ((long long)blockIdx.x * 256 + threadIdx.x) * 8;
    if (e >= (long long)(NSITES + 1) * CIN) return;
    s16x8 o;
    if (e < (long long)NSITES * CIN) {
        float4 v0 = *(const float4*)(x + e);
        float4 v1 = *(const float4*)(x + e + 4);
        o[0] = (short)f2bf(v0.x); o[1] = (short)f2bf(v0.y);
        o[2] = (short)f2bf(v0.z); o[3] = (short)f2bf(v0.w);
        o[4] = (short)f2bf(v1.x); o[5] = (short)f2bf(v1.y);
        o[6] = (short)f2bf(v1.z); o[7] = (short)f2bf(v1.w);
    } else {
#pragma unroll
        for (int j = 0; j < 8; ++j) o[j] = 0;
    }
    *(s16x8*)(xb + e) = o;
}

// ---------- gather-GEMM conv: producer/consumer wave split ----------
// y[n0+r, :] = sum_k xin[nbr[r,k]] @ Wt[k]^T ; Wt layout [nk][COUT][CK] bf16.
// Block: 320 thr = 5 waves. Waves 0-3: consumers (wave w owns cols [32w,32w+32));
// wave 4: producer, DMAs gather sets into a 4-deep LDS ring via global_load_lds.
// Why: vmcnt is in-order per wave — any wait on a recent load drains ALL older
// loads. With mixed streams (B loads + gathers in one wave), each iter's B-wait
// drained the gather prefetch (round-1 null). Split streams: producer's vmcnt
// has only gathers (counted waits, never 0 mid-loop => 2-3 iters of flight);
// consumers' vmcnt has only L2-hot B loads (~300cy waits).
// LDS sets are linear (DMA requirement); bank conflicts fixed by the rule-21
// involution: source chunk pre-swizzled c^=(row&7), read addr same XOR
// (row&7 == m&7 for MFMA rows, so read swizzle is a per-lane constant).
template <int CK, bool IDENT_FUSE, bool STATS>
__global__ __launch_bounds__(320, 4) void conv_kernel(
    const u16* __restrict__ xin, const int* __restrict__ nbr,
    const u16* __restrict__ Wt, u16* __restrict__ yout,
    float* __restrict__ psum, float* __restrict__ psq, int nk,
    const u16* __restrict__ Wskt, float* __restrict__ outid) {
    constexpr int KSTEPS = CK / 32;
    constexpr int CPR = CK / 8;            // 16B chunks per row
    constexpr int SET_ELEMS = 64 * CK;     // one gather set: 64 rows x CK bf16 (linear)
    constexpr int GLD_PER_SET = (64 * CK * 2) / 1024;  // 1KB (64 lanes x 16B) per DMA instr
    constexpr int RPI = 1024 / (CK * 2);   // rows covered per DMA instr
    __shared__ __align__(16) u16 a_tile[4 * SET_ELEMS];
    __shared__ int nbr_tile[64 * KOFFS];

    const int tid = threadIdx.x;
    const int wave = tid >> 6;
    const int lane = tid & 63;
    const int m = lane & 15;
    const int q = lane >> 4;
    const int n0 = blockIdx.x * 64;
    const int wc = wave * 32;

    for (int i = tid; i < 64 * KOFFS; i += 320) {
        int r = i / KOFFS;
        int kk = i - r * KOFFS;
        int row = n0 + r;
        nbr_tile[i] = (row < NSITES) ? nbr[row * KOFFS + kk] : NSITES;
    }
    __syncthreads();  // nbr_tile ready; also drains everyone's vmcnt to a clean 0

    f32x4 acc[4][2];
#pragma unroll
    for (int rt = 0; rt < 4; ++rt)
#pragma unroll
        for (int ct = 0; ct < 2; ++ct)
#pragma unroll
            for (int r = 0; r < 4; ++r) acc[rt][ct][r] = 0.0f;

    // producer: DMA the gather set for offset kt into ring slot kt&3.
    // DMA instr j, lane l covers row r = j*RPI + l/CPR, dest chunk c = l%CPR;
    // source fetches logical chunk c^(r&7) so linear LDS holds the swizzled tile.
    auto issue_set = [&](int kt) {
        u16* dst = a_tile + (kt & 3) * SET_ELEMS;
        const int r_ = lane / CPR;
        const int c_ = lane % CPR;
#pragma unroll
        for (int j = 0; j < GLD_PER_SET; ++j) {
            int r = j * RPI + r_;
            int cl = c_ ^ (r & 7);
            const u16* src = xin + (long long)nbr_tile[r * KOFFS + kt] * CK + cl * 8;
            gld_lds16(src, dst + j * 512);
        }
    };

    // prologue: fill 3 sets, guarantee set 0 landed (counted wait targets oldest)
    if (wave == 4) {
        issue_set(0);
        if (nk > 1) issue_set(1);
        if (nk > 2) issue_set(2);
        const int younger = ((nk > 1) ? 1 : 0) + ((nk > 2) ? 1 : 0);
        if constexpr (CK == 128) {
            if (younger == 2)      asm volatile("s_waitcnt vmcnt(32)" ::: "memory");
            else if (younger == 1) asm volatile("s_waitcnt vmcnt(16)" ::: "memory");
            else                   asm volatile("s_waitcnt vmcnt(0)" ::: "memory");
        } else {
            if (younger == 2)      asm volatile("s_waitcnt vmcnt(16)" ::: "memory");
            else if (younger == 1) asm volatile("s_waitcnt vmcnt(8)" ::: "memory");
            else                   asm volatile("s_waitcnt vmcnt(0)" ::: "memory");
        }
    }
    lds_barrier();  // set 0 visible to consumers

    for (int k = 0; k < nk; ++k) {
        if (wave == 4) {
            // ring slot (k+3)&3 was last read at iter k-1 -> free now
            if (k + 3 < nk) issue_set(k + 3);
            if (k + 1 < nk) {
                const int younger = ((k + 2 < nk) ? 1 : 0) + ((k + 3 < nk) ? 1 : 0);
                if constexpr (CK == 128) {
                    if (younger == 2)      asm volatile("s_waitcnt vmcnt(32)" ::: "memory");
                    else if (younger == 1) asm volatile("s_waitcnt vmcnt(16)" ::: "memory");
                    else                   asm volatile("s_waitcnt vmcnt(0)" ::: "memory");
                } else {
                    if (younger == 2)      asm volatile("s_waitcnt vmcnt(16)" ::: "memory");
                    else if (younger == 1) asm volatile("s_waitcnt vmcnt(8)" ::: "memory");
                    else                   asm volatile("s_waitcnt vmcnt(0)" ::: "memory");
                }
            }
        } else {
            // consumers: B fragments (L2-hot; only vmem in this wave's loop stream)
            s16x8 bf[2][KSTEPS];
            const u16* wb = Wt + (long long)k * (COUT * CK);
#pragma unroll
            for (int ct = 0; ct < 2; ++ct)
#pragma unroll
                for (int ks = 0; ks < KSTEPS; ++ks)
                    bf[ct][ks] = *(const s16x8*)(wb + (wc + ct * 16 + m) * CK + ks * 32 + q * 8);

            const u16* aset = a_tile + (k & 3) * SET_ELEMS;
#pragma unroll
            for (int ks = 0; ks < KSTEPS; ++ks) {
                s16x8 af[4];
#pragma unroll
                for (int rt = 0; rt < 4; ++rt)  // row&7 == m&7 since rt*16 % 8 == 0
                    af[rt] = *(const s16x8*)(aset + (rt * 16 + m) * CK + (((ks * 4 + q) ^ (m & 7)) * 8));
#pragma unroll
                for (int rt = 0; rt < 4; ++rt)
#pragma unroll
                    for (int ct = 0; ct < 2; ++ct)
                        acc[rt][ct] = __builtin_amdgcn_mfma_f32_16x16x32_bf16(
                            af[rt], bf[ct][ks], acc[rt][ct], 0, 0, 0);
            }
        }
        lds_barrier();  // set k+1 visible; slot (k+4)&3 free for next iter's DMA
    }

    // Store y (bf16): C/D layout col=lane&15, row=(lane>>4)*4+reg  [m89-verified]
    if (wave < 4) {
#pragma unroll
        for (int rt = 0; rt < 4; ++rt) {
            int rowb = n0 + rt * 16 + q * 4;
#pragma unroll
            for (int ct = 0; ct < 2; ++ct) {
                int col = wc + ct * 16 + m;
#pragma unroll
                for (int r = 0; r < 4; ++r) {
                    int row = rowb + r;
                    if (row < NSITES) yout[(long long)row * COUT + col] = f2bf(acc[rt][ct][r]);
                }
            }
        }

        if (STATS) {
#pragma unroll
            for (int ct = 0; ct < 2; ++ct) {
                float s = 0.f, ss = 0.f;
#pragma unroll
                for (int rt = 0; rt < 4; ++rt)
#pragma unroll
                    for (int r = 0; r < 4; ++r) {
                        float v = acc[rt][ct][r];
                        s += v; ss += v * v;
                    }
                s += __shfl_xor(s, 16); ss += __shfl_xor(ss, 16);
                s += __shfl_xor(s, 32); ss += __shfl_xor(ss, 32);
                if (q == 0) {
                    int col = wc + ct * 16 + m;
                    int slot = blockIdx.x & 63;  // 64-slot tree cuts atomic contention
                    atomicAdd(psum + slot * COUT + col, s);
                    atomicAdd(psq + slot * COUT + col, ss);
                }
            }
        }
    }

    if (IDENT_FUSE) {
        // identity = x @ W_skip for the same 64 rows (sequential, no gather).
        // All 320 threads stage set 0 (swizzled write), waves 0-3 compute.
        for (int idx = tid; idx < 64 * CPR; idx += 320) {
            int r = idx / CPR, c = idx - r * CPR;
            int row = n0 + r;
            long long gidx = (row < NSITES) ? row : NSITES;
            s16x8 v = *(const s16x8*)(xin + gidx * CK + c * 8);
            *(s16x8*)(a_tile + r * CK + ((c ^ (r & 7)) * 8)) = v;
        }
        lds_barrier();
        if (wave < 4) {
#pragma unroll
            for (int rt = 0; rt < 4; ++rt)
#pragma unroll
                for (int ct = 0; ct < 2; ++ct)
#pragma unroll
                    for (int r = 0; r < 4; ++r) acc[rt][ct][r] = 0.0f;
            s16x8 bfi[2][KSTEPS];
#pragma unroll
            for (int ct = 0; ct < 2; ++ct)
#pragma unroll
                for (int ks = 0; ks < KSTEPS; ++ks)
                    bfi[ct][ks] = *(const s16x8*)(Wskt + (wc + ct * 16 + m) * CK + ks * 32 + q * 8);
#pragma unroll
            for (int ks = 0; ks < KSTEPS; ++ks) {
                s16x8 af[4];
#pragma unroll
                for (int rt = 0; rt < 4; ++rt)
                    af[rt] = *(const s16x8*)(a_tile + (rt * 16 + m) * CK + (((ks * 4 + q) ^ (m & 7)) * 8));
#pragma unroll
                for (int rt = 0; rt < 4; ++rt)
#pragma unroll
                    for (int ct = 0; ct < 2; ++ct)
                        acc[rt][ct] = __builtin_amdgcn_mfma_f32_16x16x32_bf16(
                            af[rt], bfi[ct][ks], acc[rt][ct], 0, 0, 0);
            }
#pragma unroll
            for (int rt = 0; rt < 4; ++rt) {
                int rowb = n0 + rt * 16 + q * 4;
#pragma unroll
                for (int ct = 0; ct < 2; ++ct) {
                    int col = wc + ct * 16 + m;
#pragma unroll
                    for (int r = 0; r < 4; ++r) {
                        int row = rowb + r;
                        if (row < NSITES) outid[(long long)row * COUT + col] = acc[rt][ct][r];
                    }
                }
            }
        }
    }
}

// ---------- reduce 64 slots -> per-column affine (a = gamma*rsqrt(var+eps), b = beta - mu*a) ----------
__global__ void bn_stats_kernel(const float* __restrict__ psum, const float* __restrict__ psq,
                                const float* __restrict__ gamma, const float* __restrict__ beta,
                                float* __restrict__ ab) {
    int col = threadIdx.x;  // 128 threads
    float s = 0.f, ss = 0.f;
    for (int i = 0; i < 64; ++i) { s += psum[i * COUT + col]; ss += psq[i * COUT + col]; }
    const float inv_n = 1.0f / (float)NSITES;
    float mu = s * inv_n;
    float var = ss * inv_n - mu * mu;
    float rs = rsqrtf(var + 1e-5f);
    float a = gamma[col] * rs;
    ab[col] = a;
    ab[COUT + col] = beta[col] - mu * a;
}

// ---------- h = bf16(relu(y*a+b)), plus zero sentinel row; y is bf16 ----------
__global__ void bn_apply_kernel(const u16* __restrict__ y, const float* __restrict__ ab,
                                u16* __restrict__ h) {
    long long e = ((long long)blockIdx.x * 256 + threadIdx.x) * 8;
    if (e >= (long long)(NSITES + 1) * COUT) return;
    s16x8 o;
    if (e < (long long)NSITES * COUT) {
        int cb = (int)(e & (COUT - 1));
        s16x8 v = *(const s16x8*)(y + e);
#pragma unroll
        for (int j = 0; j < 8; ++j) {
            float r = bf2f((u16)v[j]) * ab[cb + j] + ab[COUT + cb + j];
            o[j] = (short)f2bf(fmaxf(r, 0.f));
        }
    } else {
#pragma unroll
        for (int j = 0; j < 8; ++j) o[j] = 0;
    }
    *(s16x8*)(h + e) = o;
}

// ---------- out = relu(y*a+b) + identity (identity resident in d_out); y is bf16 ----------
__global__ void final_kernel(const u16* __restrict__ y, const float* __restrict__ ab,
                             float* __restrict__ out) {
    long long e = ((long long)blockIdx.x * 256 + threadIdx.x) * 8;
    if (e >= (long long)NSITES * COUT) return;
    int cb = (int)(e & (COUT - 1));
    s16x8 v = *(const s16x8*)(y + e);
    float4 i0 = *(const float4*)(out + e);
    float4 i1 = *(const float4*)(out + e + 4);
    float is[8] = {i0.x, i0.y, i0.z, i0.w, i1.x, i1.y, i1.z, i1.w};
    float os[8];
#pragma unroll
    for (int j = 0; j < 8; ++j) {
        float r = bf2f((u16)v[j]) * ab[cb + j] + ab[COUT + cb + j];
        os[j] = fmaxf(r, 0.f) + is[j];
    }
    *(float4*)(out + e) = make_float4(os[0], os[1], os[2], os[3]);
    *(float4*)(out + e + 4) = make_float4(os[4], os[5], os[6], os[7]);
}

extern "C" void kernel_launch(void* const* d_in, const int* in_sizes, int n_in,
                              void* d_out, int out_size, void* d_ws, size_t ws_size,
                              hipStream_t stream) {
    const float* x   = (const float*)d_in[0];
    const int*   nbr = (const int*)d_in[1];
    const float* W1  = (const float*)d_in[2];
    const float* g1  = (const float*)d_in[3];
    const float* b1  = (const float*)d_in[4];
    const float* W2  = (const float*)d_in[5];
    const float* g2  = (const float*)d_in[6];
    const float* b2  = (const float*)d_in[7];
    const float* Wsk = (const float*)d_in[8];
    float* out = (float*)d_out;

    // workspace layout (bytes, 16B-aligned); total ~66 MB
    char* ws = (char*)d_ws;
    u16*   xb   = (u16*)(ws);                    // (N+1)*64 bf16      = 12,800,128 B
    u16*   W1t  = (u16*)(ws + 12800128);         // 27*128*64 bf16     =    442,368 B
    u16*   W2t  = (u16*)(ws + 13242496);         // 27*128*128 bf16    =    884,736 B
    u16*   Wskt = (u16*)(ws + 14127232);         // 128*64 bf16        =     16,384 B
    u16*   y    = (u16*)(ws + 14143616);         // N*128 bf16         = 25,600,000 B
    u16*   h1   = (u16*)(ws + 39743616);         // (N+1)*128 bf16     = 25,600,256 B
    float* ps1  = (float*)(ws + 65343872);       // 4 * 64*128 f32 partials
    float* pq1  = ps1 + 8192;
    float* ps2  = pq1 + 8192;
    float* pq2  = ps2 + 8192;
    float* ab1  = pq2 + 8192;                    // 2*2*128 f32 affine params
    float* ab2  = ab1 + 256;

    const int NBLK = (NSITES + 63) / 64;  // 1563

    prep_kernel<<<2752, 256, 0, stream>>>(W1, W2, Wsk, W1t, W2t, Wskt, ps1);
    convert_x_kernel<<<3126, 256, 0, stream>>>(x, xb);
    // conv1 + fused stats + fused identity (identity -> d_out)
    conv_kernel<64, true, true><<<NBLK, 320, 0, stream>>>(xb, nbr, W1t, y, ps1, pq1, KOFFS, Wskt, out);
    bn_stats_kernel<<<1, 128, 0, stream>>>(ps1, pq1, g1, b1, ab1);
    bn_apply_kernel<<<6251, 256, 0, stream>>>(y, ab1, h1);
    // conv2 + fused stats (reuses y buffer)
    conv_kernel<128, false, true><<<NBLK, 320, 0, stream>>>(h1, nbr, W2t, y, ps2, pq2, KOFFS, nullptr, nullptr);
    bn_stats_kernel<<<1, 128, 0, stream>>>(ps2, pq2, g2, b2, ab2);
    final_kernel<<<6250, 256, 0, stream>>>(y, ab2, out);
}

// Round 3
// 446.283 us; speedup vs baseline: 1.2737x; 1.2737x over previous
//
#include <hip/hip_runtime.h>
#include <hip/hip_bf16.h>

#define NSITES 100000
#define KOFFS 27
#define CIN 64
#define COUT 128

typedef unsigned short u16;
typedef __attribute__((ext_vector_type(8))) short s16x8;
typedef __attribute__((ext_vector_type(4))) float f32x4;

static __device__ __forceinline__ u16 f2bf(float f) {
    union { float f; unsigned u; } x; x.f = f;
    return (u16)((x.u + 0x7FFFu + ((x.u >> 16) & 1u)) >> 16);
}
static __device__ __forceinline__ float bf2f(u16 v) {
    union { unsigned u; float f; } x; x.u = ((unsigned)v) << 16;
    return x.f;
}

// Barrier with LDS-visibility only: drains ds-writes (lgkmcnt), leaves global
// loads (gather/B prefetch) in flight. __syncthreads would drain vmcnt(0).
static __device__ __forceinline__ void lds_barrier() {
    asm volatile("s_waitcnt lgkmcnt(0)" ::: "memory");
    __builtin_amdgcn_s_barrier();
    __builtin_amdgcn_sched_barrier(0);  // no hoisting of LDS ops across the barrier
}

// ---------- prep: transpose/convert weights to bf16 [k][d][c], zero stat partials ----------
__global__ void prep_kernel(const float* __restrict__ W1, const float* __restrict__ W2,
                            const float* __restrict__ Wsk,
                            u16* __restrict__ W1t, u16* __restrict__ W2t,
                            u16* __restrict__ Wskt, float* __restrict__ zero_area) {
    int i = blockIdx.x * 256 + threadIdx.x;
    if (i < 27 * 64 * 128) {
        int k = i / 8192, r = i & 8191, d = r >> 6, c = r & 63;
        W1t[i] = f2bf(W1[k * 8192 + c * 128 + d]);
        return;
    }
    i -= 27 * 64 * 128;
    if (i < 27 * 128 * 128) {
        int k = i / 16384, r = i & 16383, d = r >> 7, c = r & 127;
        W2t[i] = f2bf(W2[k * 16384 + c * 128 + d]);
        return;
    }
    i -= 27 * 128 * 128;
    if (i < 8192) {
        int d = i >> 6, c = i & 63;
        Wskt[i] = f2bf(Wsk[c * 128 + d]);
        return;
    }
    i -= 8192;
    zero_area[i] = 0.0f;  // 4 * 64*128 partial-stat floats
}

// ---------- x (fp32) -> bf16 rows, plus zero sentinel row N ----------
__global__ void convert_x_kernel(const float* __restrict__ x, u16* __restrict__ xb) {
    long long e = ((long long)blockIdx.x * 256 + threadIdx.x) * 8;
    if (e >= (long long)(NSITES + 1) * CIN) return;
    s16x8 o;
    if (e < (long long)NSITES * CIN) {
        float4 v0 = *(const float4*)(x + e);
        float4 v1 = *(const float4*)(x + e + 4);
        o[0] = (short)f2bf(v0.x); o[1] = (short)f2bf(v0.y);
        o[2] = (short)f2bf(v0.z); o[3] = (short)f2bf(v0.w);
        o[4] = (short)f2bf(v1.x); o[5] = (short)f2bf(v1.y);
        o[6] = (short)f2bf(v1.z); o[7] = (short)f2bf(v1.w);
    } else {
#pragma unroll
        for (int j = 0; j < 8; ++j) o[j] = 0;
    }
    *(s16x8*)(xb + e) = o;
}

// ---------- gather-GEMM conv: ordering-correct 2-deep pipeline ----------
// y[n0+r, :] = sum_k xin[nbr[r,k]] @ Wt[k]^T ; Wt layout [nk=27][COUT][CK] bf16.
// Block: 256 thr = 4 waves, 64-row tile; wave w owns output cols [32w, 32w+32).
// Key invariant (fixes rounds 0-2): B_k is loaded TWO iterations early and every
// B-issue precedes the next G-issue in program order. vmcnt is an in-order
// counter, so the only per-iteration wait (ds_write needs G_{k+1}) leaves
// B_{k+1}, G_{k+2}, B_{k+2}, G_{k+3} in flight, and the MFMA needs no fresh
// wait (B_k became complete with the G_{k+1} wait). Rounds 0/1 loaded B_k in
// iteration k, so waiting on it drained ALL older gathers every iteration.
// Main loop is branch-free (tail peeled) so compiler waitcnt counting is exact.
template <int CK, bool IDENT_FUSE, bool STATS>
__global__ __launch_bounds__(256, 3) void conv_kernel(
    const u16* __restrict__ xin, const int* __restrict__ nbr,
    const u16* __restrict__ Wt, u16* __restrict__ yout,
    float* __restrict__ psum, float* __restrict__ psq, int nk_unused,
    const u16* __restrict__ Wskt, float* __restrict__ outid) {
    constexpr int STRIDE = CK + 4;   // +4 bf16 pad (round-1 conflict level)
    constexpr int KSTEPS = CK / 32;
    constexpr int CPR = CK / 8;      // 16B chunks per row
    constexpr int RPP = 256 / CPR;   // rows staged per pass
    constexpr int NPASS = 64 / RPP;
    __shared__ __align__(16) u16 a_tile[2][64 * STRIDE];
    __shared__ int nbr_tile[64 * KOFFS];

    const int tid = threadIdx.x;
    const int wave = tid >> 6;
    const int lane = tid & 63;
    const int m = lane & 15;
    const int q = lane >> 4;
    const int n0 = blockIdx.x * 64;
    const int wc = wave * 32;
    const int srow = tid / CPR;
    const int schunk = tid % CPR;

    for (int i = tid; i < 64 * KOFFS; i += 256) {
        int r = i / KOFFS;
        int kk = i - r * KOFFS;
        int row = n0 + r;
        nbr_tile[i] = (row < NSITES) ? nbr[row * KOFFS + kk] : NSITES;
    }
    __syncthreads();  // nbr_tile ready; clean vmcnt slate

    f32x4 acc[4][2];
#pragma unroll
    for (int rt = 0; rt < 4; ++rt)
#pragma unroll
        for (int ct = 0; ct < 2; ++ct)
#pragma unroll
            for (int r = 0; r < 4; ++r) acc[rt][ct][r] = 0.0f;

    s16x8 gA[NPASS], gB[NPASS];          // gather register sets (A-rows)
    s16x8 bA[2][KSTEPS], bB[2][KSTEPS];  // B fragment sets

    auto gload = [&](s16x8 (&g)[NPASS], int kk) {
#pragma unroll
        for (int p = 0; p < NPASS; ++p) {
            int r = p * RPP + srow;
            g[p] = *(const s16x8*)(xin + (long long)nbr_tile[r * KOFFS + kk] * CK + schunk * 8);
        }
    };
    auto bload = [&](s16x8 (&b)[2][KSTEPS], int kk) {
        const u16* wb = Wt + (long long)kk * (COUT * CK);
#pragma unroll
        for (int ct = 0; ct < 2; ++ct)
#pragma unroll
            for (int ks = 0; ks < KSTEPS; ++ks)
                b[ct][ks] = *(const s16x8*)(wb + (wc + ct * 16 + m) * CK + ks * 32 + q * 8);
    };
    auto awrite = [&](s16x8 (&g)[NPASS], int buf) {
#pragma unroll
        for (int p = 0; p < NPASS; ++p)
            *(s16x8*)(&a_tile[buf][(p * RPP + srow) * STRIDE + schunk * 8]) = g[p];
    };
    auto mfma_from = [&](int buf, s16x8 (&b)[2][KSTEPS]) {
        __builtin_amdgcn_s_setprio(1);
#pragma unroll
        for (int ks = 0; ks < KSTEPS; ++ks) {
            s16x8 af[4];
#pragma unroll
            for (int rt = 0; rt < 4; ++rt)
                af[rt] = *(const s16x8*)(&a_tile[buf][(rt * 16 + m) * STRIDE + ks * 32 + q * 8]);
#pragma unroll
            for (int rt = 0; rt < 4; ++rt)
#pragma unroll
                for (int ct = 0; ct < 2; ++ct)
                    acc[rt][ct] = __builtin_amdgcn_mfma_f32_16x16x32_bf16(
                        af[rt], b[ct][ks], acc[rt][ct], 0, 0, 0);
        }
        __builtin_amdgcn_s_setprio(0);
    };

    // prologue — establishes the invariant (each B_j issued before G_{j+1}):
    gload(gA, 0);      // G_0
    bload(bA, 0);      // B_0  (older than G_1)
    awrite(gA, 0);     // stage A_0 into buf0 (wait covers only G_0; B_0 stays in flight)
    gload(gA, 1);      // G_1  (set A regs free after ds_write consumed them)
    bload(bB, 1);      // B_1  (older than G_2)
    gload(gB, 2);      // G_2
    lds_barrier();     // buf0 visible

    // iter k: [awrite A_{k+1} (wait: G_{k+1})] [issue G_{k+3}] [barrier]
    //         [MFMA buf[k&1] x B_k] [issue B_{k+2} into the just-consumed set] [barrier]
    auto conv_iter = [&](int k, s16x8 (&g)[NPASS], s16x8 (&bcur)[2][KSTEPS]) {
        awrite(g, (k + 1) & 1);
        gload(g, k + 3);
        lds_barrier();            // A_{k+1} staged; prev readers of buf[(k+1)&1] done earlier
        mfma_from(k & 1, bcur);
        bload(bcur, k + 2);       // refill same set for iter k+2 (B issued after this MFMA,
                                  // before iter k+1's G_{k+4} -> ordering invariant holds)
        lds_barrier();            // MFMA reads of buf[k&1] done before iter k+1's awrite
    };

    // branch-free main loop: k = 0..23 (k+3 <= 26 always in range)
    for (int k = 0; k < 24; k += 2) {
        conv_iter(k, gA, bA);
        conv_iter(k + 1, gB, bB);
    }
    // peeled tail k = 24, 25, 26 (KOFFS = 27)
    awrite(gA, 1);                 // A_25
    lds_barrier();
    mfma_from(0, bA);              // B_24
    bload(bA, 26);                 // B_26 for iter 26
    lds_barrier();
    awrite(gB, 0);                 // A_26
    lds_barrier();
    mfma_from(1, bB);              // B_25
    lds_barrier();
    mfma_from(0, bA);              // B_26 (compiler inserts exact wait for bA)

    // Store y (bf16): C/D layout col=lane&15, row=(lane>>4)*4+reg  [m89-verified]
#pragma unroll
    for (int rt = 0; rt < 4; ++rt) {
        int rowb = n0 + rt * 16 + q * 4;
#pragma unroll
        for (int ct = 0; ct < 2; ++ct) {
            int col = wc + ct * 16 + m;
#pragma unroll
            for (int r = 0; r < 4; ++r) {
                int row = rowb + r;
                if (row < NSITES) yout[(long long)row * COUT + col] = f2bf(acc[rt][ct][r]);
            }
        }
    }

    if (STATS) {
#pragma unroll
        for (int ct = 0; ct < 2; ++ct) {
            float s = 0.f, ss = 0.f;
#pragma unroll
            for (int rt = 0; rt < 4; ++rt)
#pragma unroll
                for (int r = 0; r < 4; ++r) {
                    float v = acc[rt][ct][r];
                    s += v; ss += v * v;
                }
            s += __shfl_xor(s, 16); ss += __shfl_xor(ss, 16);
            s += __shfl_xor(s, 32); ss += __shfl_xor(ss, 32);
            if (q == 0) {
                int col = wc + ct * 16 + m;
                int slot = blockIdx.x & 63;  // 64-slot tree cuts atomic contention
                atomicAdd(psum + slot * COUT + col, s);
                atomicAdd(psq + slot * COUT + col, ss);
            }
        }
    }

    if (IDENT_FUSE) {
        // identity = x @ W_skip for the same 64 rows (no gather); reuses acc regs
        lds_barrier();  // last MFMA's reads of a_tile[0] done before restaging
#pragma unroll
        for (int rt = 0; rt < 4; ++rt)
#pragma unroll
            for (int ct = 0; ct < 2; ++ct)
#pragma unroll
                for (int r = 0; r < 4; ++r) acc[rt][ct][r] = 0.0f;
        s16x8 aid[NPASS];
#pragma unroll
        for (int p = 0; p < NPASS; ++p) {
            int row = n0 + p * RPP + srow;
            long long idx = (row < NSITES) ? row : NSITES;
            aid[p] = *(const s16x8*)(xin + idx * CK + schunk * 8);
        }
        s16x8 bfi[2][KSTEPS];
#pragma unroll
        for (int ct = 0; ct < 2; ++ct)
#pragma unroll
            for (int ks = 0; ks < KSTEPS; ++ks)
                bfi[ct][ks] = *(const s16x8*)(Wskt + (wc + ct * 16 + m) * CK + ks * 32 + q * 8);
        awrite(aid, 0);
        lds_barrier();
        mfma_from(0, bfi);
#pragma unroll
        for (int rt = 0; rt < 4; ++rt) {
            int rowb = n0 + rt * 16 + q * 4;
#pragma unroll
            for (int ct = 0; ct < 2; ++ct) {
                int col = wc + ct * 16 + m;
#pragma unroll
                for (int r = 0; r < 4; ++r) {
                    int row = rowb + r;
                    if (row < NSITES) outid[(long long)row * COUT + col] = acc[rt][ct][r];
                }
            }
        }
    }
}

// ---------- reduce 64 slots -> per-column affine (a = gamma*rsqrt(var+eps), b = beta - mu*a) ----------
__global__ void bn_stats_kernel(const float* __restrict__ psum, const float* __restrict__ psq,
                                const float* __restrict__ gamma, const float* __restrict__ beta,
                                float* __restrict__ ab) {
    int col = threadIdx.x;  // 128 threads
    float s = 0.f, ss = 0.f;
    for (int i = 0; i < 64; ++i) { s += psum[i * COUT + col]; ss += psq[i * COUT + col]; }
    const float inv_n = 1.0f / (float)NSITES;
    float mu = s * inv_n;
    float var = ss * inv_n - mu * mu;
    float rs = rsqrtf(var + 1e-5f);
    float a = gamma[col] * rs;
    ab[col] = a;
    ab[COUT + col] = beta[col] - mu * a;
}

// ---------- h = bf16(relu(y*a+b)), plus zero sentinel row; y is bf16 ----------
__global__ void bn_apply_kernel(const u16* __restrict__ y, const float* __restrict__ ab,
                                u16* __restrict__ h) {
    long long e = ((long long)blockIdx.x * 256 + threadIdx.x) * 8;
    if (e >= (long long)(NSITES + 1) * COUT) return;
    s16x8 o;
    if (e < (long long)NSITES * COUT) {
        int cb = (int)(e & (COUT - 1));
        s16x8 v = *(const s16x8*)(y + e);
#pragma unroll
        for (int j = 0; j < 8; ++j) {
            float r = bf2f((u16)v[j]) * ab[cb + j] + ab[COUT + cb + j];
            o[j] = (short)f2bf(fmaxf(r, 0.f));
        }
    } else {
#pragma unroll
        for (int j = 0; j < 8; ++j) o[j] = 0;
    }
    *(s16x8*)(h + e) = o;
}

// ---------- out = relu(y*a+b) + identity (identity resident in d_out); y is bf16 ----------
__global__ void final_kernel(const u16* __restrict__ y, const float* __restrict__ ab,
                             float* __restrict__ out) {
    long long e = ((long long)blockIdx.x * 256 + threadIdx.x) * 8;
    if (e >= (long long)NSITES * COUT) return;
    int cb = (int)(e & (COUT - 1));
    s16x8 v = *(const s16x8*)(y + e);
    float4 i0 = *(const float4*)(out + e);
    float4 i1 = *(const float4*)(out + e + 4);
    float is[8] = {i0.x, i0.y, i0.z, i0.w, i1.x, i1.y, i1.z, i1.w};
    float os[8];
#pragma unroll
    for (int j = 0; j < 8; ++j) {
        float r = bf2f((u16)v[j]) * ab[cb + j] + ab[COUT + cb + j];
        os[j] = fmaxf(r, 0.f) + is[j];
    }
    *(float4*)(out + e) = make_float4(os[0], os[1], os[2], os[3]);
    *(float4*)(out + e + 4) = make_float4(os[4], os[5], os[6], os[7]);
}

extern "C" void kernel_launch(void* const* d_in, const int* in_sizes, int n_in,
                              void* d_out, int out_size, void* d_ws, size_t ws_size,
                              hipStream_t stream) {
    const float* x   = (const float*)d_in[0];
    const int*   nbr = (const int*)d_in[1];
    const float* W1  = (const float*)d_in[2];
    const float* g1  = (const float*)d_in[3];
    const float* b1  = (const float*)d_in[4];
    const float* W2  = (const float*)d_in[5];
    const float* g2  = (const float*)d_in[6];
    const float* b2  = (const float*)d_in[7];
    const float* Wsk = (const float*)d_in[8];
    float* out = (float*)d_out;

    // workspace layout (bytes, 16B-aligned); total ~66 MB
    char* ws = (char*)d_ws;
    u16*   xb   = (u16*)(ws);                    // (N+1)*64 bf16      = 12,800,128 B
    u16*   W1t  = (u16*)(ws + 12800128);         // 27*128*64 bf16     =    442,368 B
    u16*   W2t  = (u16*)(ws + 13242496);         // 27*128*128 bf16    =    884,736 B
    u16*   Wskt = (u16*)(ws + 14127232);         // 128*64 bf16        =     16,384 B
    u16*   y    = (u16*)(ws + 14143616);         // N*128 bf16         = 25,600,000 B
    u16*   h1   = (u16*)(ws + 39743616);         // (N+1)*128 bf16     = 25,600,256 B
    float* ps1  = (float*)(ws + 65343872);       // 4 * 64*128 f32 partials
    float* pq1  = ps1 + 8192;
    float* ps2  = pq1 + 8192;
    float* pq2  = ps2 + 8192;
    float* ab1  = pq2 + 8192;                    // 2*2*128 f32 affine params
    float* ab2  = ab1 + 256;

    const int NBLK = (NSITES + 63) / 64;  // 1563

    prep_kernel<<<2752, 256, 0, stream>>>(W1, W2, Wsk, W1t, W2t, Wskt, ps1);
    convert_x_kernel<<<3126, 256, 0, stream>>>(x, xb);
    // conv1 + fused stats + fused identity (identity -> d_out)
    conv_kernel<64, true, true><<<NBLK, 256, 0, stream>>>(xb, nbr, W1t, y, ps1, pq1, KOFFS, Wskt, out);
    bn_stats_kernel<<<1, 128, 0, stream>>>(ps1, pq1, g1, b1, ab1);
    bn_apply_kernel<<<6251, 256, 0, stream>>>(y, ab1, h1);
    // conv2 + fused stats (reuses y buffer)
    conv_kernel<128, false, true><<<NBLK, 256, 0, stream>>>(h1, nbr, W2t, y, ps2, pq2, KOFFS, nullptr, nullptr);
    bn_stats_kernel<<<1, 128, 0, stream>>>(ps2, pq2, g2, b2, ab2);
    final_kernel<<<6250, 256, 0, stream>>>(y, ab2, out);
}